// Round 7
// baseline (387.162 us; speedup 1.0000x reference)
//
#include <hip/hip_runtime.h>
#include <hip/hip_bf16.h>

typedef __attribute__((ext_vector_type(8))) short short8;
typedef __attribute__((ext_vector_type(4))) short short4v;
typedef __attribute__((ext_vector_type(4))) float f32x4;

#define INV_TEMP 0.044194173824159216f

__device__ __forceinline__ ushort f2bf(float f) {
  unsigned u = __float_as_uint(f);
  unsigned r = (u + 0x7FFFu + ((u >> 16) & 1u)) >> 16;   // RNE
  return (ushort)r;
}
__device__ __forceinline__ float bf2f(ushort u) {
  union { unsigned i; float f; } x; x.i = ((unsigned)u) << 16; return x.f;
}

// async global->LDS, 16B per lane. LDS dest = wave-uniform base + lane*16;
// global source is per-lane (carries the inverse swizzle).
__device__ __forceinline__ void gload_lds16(const void* g, void* l) {
  __builtin_amdgcn_global_load_lds(
      (const __attribute__((address_space(1))) unsigned int*)(unsigned long long)(uintptr_t)g,
      (__attribute__((address_space(3))) unsigned int*)(unsigned)(uintptr_t)l,
      16, 0, 0);
}

// ---------------- all weight transposes in one launch ----------------
__global__ __launch_bounds__(256)
void transpose_cvt_all(const float* __restrict__ Wq, const float* __restrict__ Wk,
                       const float* __restrict__ Wv, const float* __restrict__ W1,
                       const float* __restrict__ W2,
                       ushort* __restrict__ Tq, ushort* __restrict__ Tk,
                       ushort* __restrict__ Tv, ushort* __restrict__ T1,
                       ushort* __restrict__ T2) {
  const int z = blockIdx.z;
  const int K = (z < 3) ? 1024 : 512;
  const int N = (z == 4) ? 1024 : 512;
  if (blockIdx.x * 32 >= N || blockIdx.y * 32 >= K) return;
  const float* W = z == 0 ? Wq : (z == 1 ? Wk : (z == 2 ? Wv : (z == 3 ? W1 : W2)));
  ushort* WT = z == 0 ? Tq : (z == 1 ? Tk : (z == 2 ? Tv : (z == 3 ? T1 : T2)));
  __shared__ float tile[32][33];
  const int n0 = blockIdx.x * 32, k0 = blockIdx.y * 32;
  const int tx = threadIdx.x & 31, ty = threadIdx.x >> 5;
  #pragma unroll
  for (int i = ty; i < 32; i += 8)
    tile[i][tx] = W[(long)(k0 + i) * N + n0 + tx];
  __syncthreads();
  #pragma unroll
  for (int i = ty; i < 32; i += 8)
    WT[(long)(n0 + i) * K + k0 + tx] = f2bf(tile[tx][i]);
}

// ---------------- bf16 transpose per batch: in (S,D) -> out (D,S) ----------------
__global__ __launch_bounds__(256)
void transpose_bf16(const ushort* __restrict__ in, ushort* __restrict__ out, int S, int D) {
  __shared__ ushort tile[32][33];
  const ushort* inb = in + (long)blockIdx.z * S * D;
  ushort* outb = out + (long)blockIdx.z * S * D;
  const int d0 = blockIdx.x * 32, s0 = blockIdx.y * 32;
  const int tx = threadIdx.x & 31, ty = threadIdx.x >> 5;
  #pragma unroll
  for (int i = ty; i < 32; i += 8)
    tile[i][tx] = inb[(long)(s0 + i) * D + d0 + tx];
  __syncthreads();
  #pragma unroll
  for (int i = ty; i < 32; i += 8)
    outb[(long)(d0 + i) * S + s0 + tx] = tile[tx][i];
}

// ---------------- merged LayerNorm over D=512: q from f32, k/v from bf16 ----------------
__global__ __launch_bounds__(256)
void ln3_kernel(const float* __restrict__ Xq, const ushort* __restrict__ Xk,
                const ushort* __restrict__ Xv,
                const float* __restrict__ gq, const float* __restrict__ beq,
                const float* __restrict__ gk, const float* __restrict__ bek,
                const float* __restrict__ gv, const float* __restrict__ bev,
                ushort* __restrict__ Oq, ushort* __restrict__ Ok, ushort* __restrict__ Ov) {
  const int which = blockIdx.y;
  const float* g = which == 0 ? gq : (which == 1 ? gk : gv);
  const float* be = which == 0 ? beq : (which == 1 ? bek : bev);
  ushort* out = which == 0 ? Oq : (which == 1 ? Ok : Ov);
  const float scale = which == 0 ? INV_TEMP : 1.0f;

  const int row = blockIdx.x * 4 + (threadIdx.x >> 6);
  const int lane = threadIdx.x & 63;
  f32x4 v0, v1;
  if (which == 0) {
    const float* x = Xq + (long)row * 512 + lane * 8;
    v0 = *(const f32x4*)x;
    v1 = *(const f32x4*)(x + 4);
  } else {
    const ushort* x = (which == 1 ? Xk : Xv) + (long)row * 512 + lane * 8;
    short8 vv = *(const short8*)x;
    #pragma unroll
    for (int j = 0; j < 4; j++) { v0[j] = bf2f((ushort)vv[j]); v1[j] = bf2f((ushort)vv[4 + j]); }
  }
  float s = v0[0]+v0[1]+v0[2]+v0[3]+v1[0]+v1[1]+v1[2]+v1[3];
  float ss = v0[0]*v0[0]+v0[1]*v0[1]+v0[2]*v0[2]+v0[3]*v0[3]
           + v1[0]*v1[0]+v1[1]*v1[1]+v1[2]*v1[2]+v1[3]*v1[3];
  #pragma unroll
  for (int off = 32; off; off >>= 1) { s += __shfl_xor(s, off); ss += __shfl_xor(ss, off); }
  const float mean = s * (1.0f/512.0f);
  const float var  = ss * (1.0f/512.0f) - mean*mean;
  const float rs = rsqrtf(var + 1e-6f);
  f32x4 g0 = *(const f32x4*)(g + lane*8);
  f32x4 g1 = *(const f32x4*)(g + lane*8 + 4);
  f32x4 b0 = *(const f32x4*)(be + lane*8);
  f32x4 b1 = *(const f32x4*)(be + lane*8 + 4);
  union { short8 v; ushort u[8]; } o;
  #pragma unroll
  for (int j = 0; j < 4; j++) o.u[j]     = f2bf(((v0[j]-mean)*rs*g0[j] + b0[j]) * scale);
  #pragma unroll
  for (int j = 0; j < 4; j++) o.u[4 + j] = f2bf(((v1[j]-mean)*rs*g1[j] + b1[j]) * scale);
  *(short8*)(out + (long)row * 512 + lane * 8) = o.v;
}

// ---------------- pipelined TN GEMM: C[M,N] = A[M,K] * BT[N,K]^T ----------------
// 512 threads, 8 waves (2M x 4N), per-wave 64x32 output. BK=32,
// TRIPLE-buffered LDS (48KB), stage issued at TOP of iter t for tile t+2
// -> 2 full iterations of latency cover; counted vmcnt (never 0 in steady state).
// EPI: 0 none, 1 relu, 2 exp+mask+row-sum partials,
//      3 invZ-from-partials row-scale + fused normalized-f32-attn write,
//      4 merged QKV projections (grid z selects A/B/bias/output; A is f32).
template<int EPI, bool HAS_BIAS, bool OUT_BF16, bool A_F32>
__global__ __launch_bounds__(512, 4)
void gemm_tn_pipe(const void* __restrict__ Av, const ushort* __restrict__ Bt,
                  const float* __restrict__ bias, const int* __restrict__ mask,
                  float* __restrict__ Cf, ushort* __restrict__ Cb,
                  float* __restrict__ partial,
                  const float* __restrict__ A2, const float* __restrict__ A3,
                  const ushort* __restrict__ Bt2, const ushort* __restrict__ Bt3,
                  const float* __restrict__ bias2, const float* __restrict__ bias3,
                  ushort* __restrict__ Cb2,
                  int M, int N, int K,
                  long sA, long sB, long sC, long sMask) {
  __shared__ ushort As[3][128 * 32];
  __shared__ ushort Bs[3][128 * 32];
  __shared__ float zloc[128];
  const int tid = threadIdx.x;
  const int lane = tid & 63;
  const int wave = tid >> 6;       // 0..7
  const int wr = wave >> 2;        // 0..1  (64-row slab)
  const int wc = wave & 3;         // 0..3  (32-col slab)

  // ---- XCD-aware bijective chunk swizzle (T1) ----
  const int gx = gridDim.x, gy = gridDim.y;
  int lin = blockIdx.x + gx * (blockIdx.y + gy * blockIdx.z);
  const int nwg = gx * gy * (int)gridDim.z;
  int swz = lin;
  if ((nwg & 7) == 0) {
    const int q8 = nwg >> 3;
    swz = (lin & 7) * q8 + (lin >> 3);
  }
  const int bx = swz % gx;
  const int tmp = swz / gx;
  const int by = tmp % gy;
  const int bz = tmp / gy;

  const long zb = bz;
  const float* Afp;
  const ushort* Bb;
  const float* bias_p = bias;
  if constexpr (EPI == 4) {
    Afp = (bz == 0 ? (const float*)Av : (bz == 1 ? A2 : A3)) + (long)by * 128 * K;
    Bb = (bz == 0 ? Bt : (bz == 1 ? Bt2 : Bt3)) + (long)bx * 128 * K;
    bias_p = bz == 0 ? bias : (bz == 1 ? bias2 : bias3);
  } else {
    Afp = (const float*)Av + zb * sA + (long)by * 128 * K;
    Bb = Bt + zb * sB + (long)bx * 128 * K;
  }
  const ushort* Ab = (const ushort*)Av + zb * sA + (long)by * 128 * K;
  const int rowbase0 = by * 128;
  const int nt = K >> 5;           // BK=32

  if constexpr (EPI == 3) {
    if (tid < 128) {
      float z = 0.f;
      #pragma unroll
      for (int j = 0; j < 16; j++)
        z += partial[((long)(zb * 16 + j)) * 2048 + rowbase0 + tid];
      zloc[tid] = 1.0f / z;
    }
  }

  // per-thread staging geometry: c = tid (512 granules of 16B per 8KB tile)
  const int srow = tid >> 2;       // 0..127
  const int sg   = tid & 3;        // 0..3
  const int sgsrc = sg ^ (srow & 3);
  const int sdst = tid * 16;       // linear LDS byte dest
  const int swrA = (srow << 6) | ((sg << 4) ^ ((srow & 3) << 4)); // swizzled A write (A_F32)

  auto stageB = [&](int buf, int t) {
    gload_lds16(Bb + (long)srow * K + ((long)t << 5) + sgsrc * 8, (char*)Bs[buf] + sdst);
  };
  auto stageA = [&](int buf, int t) {
    gload_lds16(Ab + (long)srow * K + ((long)t << 5) + sgsrc * 8, (char*)As[buf] + sdst);
  };
  auto loadA = [&](int t, f32x4& a0, f32x4& a1) {
    const float* p = Afp + (long)srow * K + ((long)t << 5) + sg * 8;
    a0 = *(const f32x4*)p;
    a1 = *(const f32x4*)(p + 4);
  };
  auto writeA = [&](int buf, const f32x4& a0, const f32x4& a1) {
    union { short8 s; ushort u[8]; } o;
    #pragma unroll
    for (int j = 0; j < 4; j++) { o.u[j] = f2bf(a0[j]); o.u[4 + j] = f2bf(a1[j]); }
    *(short8*)((char*)As[buf] + swrA) = o.s;
    asm volatile("s_waitcnt lgkmcnt(0)" ::: "memory");
  };

  f32x4 acc[4][2];
  #pragma unroll
  for (int m = 0; m < 4; m++)
    #pragma unroll
    for (int n = 0; n < 2; n++)
      acc[m][n] = f32x4{0.f, 0.f, 0.f, 0.f};

  // prologue: tiles 0,1 staged
  if constexpr (A_F32) {
    f32x4 p0, p1;
    loadA(0, p0, p1); writeA(0, p0, p1); stageB(0, 0);
    loadA(1, p0, p1); writeA(1, p0, p1); stageB(1, 1);
  } else {
    stageA(0, 0); stageB(0, 0);
    stageA(1, 1); stageB(1, 1);
  }

  for (int t = 0; t < nt; ++t) {
    const int buf = t % 3;
    const bool has = (t + 2 < nt);
    f32x4 na0, na1;
    if (has) {
      const int nbuf = (t + 2) % 3;
      if constexpr (A_F32) {
        loadA(t + 2, na0, na1);     // issue early (T14); write after barrier-2
        stageB(nbuf, t + 2);
      } else {
        stageA(nbuf, t + 2);
        stageB(nbuf, t + 2);
      }
    }
    const int rem = nt - 1 - t;
    if (rem == 0) {
      asm volatile("s_waitcnt vmcnt(0)" ::: "memory");
    } else if (rem == 1) {
      if constexpr (A_F32) asm volatile("s_waitcnt vmcnt(1)" ::: "memory");
      else                 asm volatile("s_waitcnt vmcnt(2)" ::: "memory");
    } else {
      asm volatile("s_waitcnt vmcnt(4)" ::: "memory");
    }
    __builtin_amdgcn_s_barrier();          // tile-t data visible to all waves
    __builtin_amdgcn_sched_barrier(0);

    // fused normalized-attn f32 write (PV): block bx owns column quarter bx
    if constexpr (EPI == 3) {
      if ((t >> 4) == bx) {
        short8 p8 = *(const short8*)((const char*)As[buf] +
                     ((srow << 6) | (((sg ^ (srow & 3))) << 4)));
        const float iz = zloc[srow];
        f32x4 o0, o1;
        #pragma unroll
        for (int jj = 0; jj < 4; jj++) {
          o0[jj] = bf2f((ushort)p8[jj]) * iz;
          o1[jj] = bf2f((ushort)p8[4 + jj]) * iz;
        }
        float* dst = Cf + zb * 4194304L + (long)(rowbase0 + srow) * 2048 + (t << 5) + sg * 8;
        *(f32x4*)dst = o0;
        *(f32x4*)(dst + 4) = o1;
      }
    }

    {
      short8 af[4], bfr[2];
      const int kb = (lane >> 4) << 4;     // 0,16,32,48 bytes = k 0..31
      #pragma unroll
      for (int m = 0; m < 4; m++) {
        const int row = wr * 64 + m * 16 + (lane & 15);
        af[m] = *(const short8*)((const char*)As[buf] +
                 ((row << 6) | (kb ^ ((row & 3) << 4))));
      }
      #pragma unroll
      for (int n = 0; n < 2; n++) {
        const int col = wc * 32 + n * 16 + (lane & 15);
        bfr[n] = *(const short8*)((const char*)Bs[buf] +
                  ((col << 6) | (kb ^ ((col & 3) << 4))));
      }
      __builtin_amdgcn_s_setprio(1);
      #pragma unroll
      for (int m = 0; m < 4; m++)
        #pragma unroll
        for (int n = 0; n < 2; n++)
          acc[m][n] = __builtin_amdgcn_mfma_f32_16x16x32_bf16(af[m], bfr[n], acc[m][n], 0, 0, 0);
      __builtin_amdgcn_s_setprio(0);
    }
    __builtin_amdgcn_sched_barrier(0);
    __builtin_amdgcn_s_barrier();          // all waves done reading buf t
    __builtin_amdgcn_sched_barrier(0);
    if (has) {
      if constexpr (A_F32) writeA((t + 2) % 3, na0, na1);
    }
  }

  // epilogue: D[row][col], col = lane&15, row = (lane>>4)*4 + r  [m89/m91 layout]
  const int colbase = bx * 128 + wc * 32;
  const int rowbase = by * 128 + wr * 64;
  const int c_lane = lane & 15;
  const int r_lane = (lane >> 4) << 2;

  float rs_acc[4][4];
  if constexpr (EPI == 2) {
    #pragma unroll
    for (int m = 0; m < 4; m++)
      #pragma unroll
      for (int r4 = 0; r4 < 4; r4++) rs_acc[m][r4] = 0.f;
  }

  #pragma unroll
  for (int n = 0; n < 2; n++) {
    const int col = colbase + n * 16 + c_lane;
    const float bv = HAS_BIAS ? bias_p[col] : 0.0f;
    #pragma unroll
    for (int m = 0; m < 4; m++) {
      const int rbase = rowbase + m * 16 + r_lane;
      #pragma unroll
      for (int r4 = 0; r4 < 4; r4++) {
        const int row = rbase + r4;
        float vv = acc[m][n][r4] + bv;
        if constexpr (EPI == 1) vv = fmaxf(vv, 0.0f);
        if constexpr (EPI == 2) {
          const int mk = mask[zb * sMask + (long)row * N + col];
          vv = mk ? __expf(vv) : 0.0f;
          rs_acc[m][r4] += vv;
        }
        if constexpr (EPI == 3) vv *= zloc[wr * 64 + m * 16 + r_lane + r4];
        const long off = zb * sC + (long)row * N + col;
        if constexpr (EPI == 4) {
          if (bz == 0) Cf[off] = vv;
          else if (bz == 1) Cb[off] = f2bf(vv);
          else Cb2[off] = f2bf(vv);
        } else if constexpr (OUT_BF16) {
          Cb[off] = f2bf(vv);
        } else {
          Cf[off] = vv;
        }
      }
    }
  }

  if constexpr (EPI == 2) {
    // deterministic per-block row sums: 16-lane reduce -> LDS -> sum 4 wc slabs
    __syncthreads();                        // As free for reuse as scratch
    float (*red)[128] = (float(*)[128])As;
    #pragma unroll
    for (int m = 0; m < 4; m++)
      #pragma unroll
      for (int r4 = 0; r4 < 4; r4++) {
        float vsum = rs_acc[m][r4];
        vsum += __shfl_xor(vsum, 1);
        vsum += __shfl_xor(vsum, 2);
        vsum += __shfl_xor(vsum, 4);
        vsum += __shfl_xor(vsum, 8);
        if (c_lane == 0) red[wc][wr * 64 + m * 16 + r_lane + r4] = vsum;
      }
    __syncthreads();
    if (tid < 128)
      partial[((long)zb * 16 + bx) * 2048 + by * 128 + tid] =
          red[0][tid] + red[1][tid] + red[2][tid] + red[3][tid];
  }
}

extern "C" void kernel_launch(void* const* d_in, const int* in_sizes, int n_in,
                              void* d_out, int out_size, void* d_ws, size_t ws_size,
                              hipStream_t stream) {
  const float* q    = (const float*)d_in[0];
  const float* k    = (const float*)d_in[1];
  const float* v    = (const float*)d_in[2];
  const int*   mask = (const int*)d_in[3];
  const float* Wq   = (const float*)d_in[4];
  const float* bq   = (const float*)d_in[5];
  const float* Wk   = (const float*)d_in[6];
  const float* bk   = (const float*)d_in[7];
  const float* Wv   = (const float*)d_in[8];
  const float* bv   = (const float*)d_in[9];
  const float* g_q  = (const float*)d_in[10];
  const float* be_q = (const float*)d_in[11];
  const float* g_k  = (const float*)d_in[12];
  const float* be_k = (const float*)d_in[13];
  const float* g_v  = (const float*)d_in[14];
  const float* be_v = (const float*)d_in[15];
  const float* W1   = (const float*)d_in[16];
  const float* b1   = (const float*)d_in[17];
  const float* W2   = (const float*)d_in[18];
  const float* b2   = (const float*)d_in[19];

  float* out_mlp  = (float*)d_out;                 // (8,2048,1024)
  float* out_res  = out_mlp + 16777216L;           // (8,2048,1,512)
  float* out_attn = out_res + 8388608L;            // (8,2048,2048)

  char* w = (char*)d_ws;
  ushort* qn      = (ushort*)(w);                   // 16.7MB
  ushort* kn      = (ushort*)(w + 16777216UL);      // 16.7MB
  ushort* kp_bf   = (ushort*)(w + 33554432UL);      // 16.7MB (dead after ln3)
  ushort* vp_bf   = (ushort*)(w + 50331648UL);      // 16.7MB (dead after ln3)
  ushort* attn_bf = (ushort*)(w + 33554432UL);      // 67MB, overlaps kp_bf/vp_bf
  ushort* vn      = (ushort*)(w + 100663296UL);     // 16.7MB
  ushort* vnT     = (ushort*)(w + 117440512UL);     // 16.7MB
  ushort* pv      = (ushort*)(w + 134217728UL);     // 16.7MB
  ushort* h       = (ushort*)(w + 150994944UL);     // 16.7MB
  ushort* wqT     = (ushort*)(w + 167772160UL);     // 1MB (512,1024)
  ushort* wkT     = (ushort*)(w + 168820736UL);
  ushort* wvT     = (ushort*)(w + 169869312UL);
  ushort* w1T     = (ushort*)(w + 170917888UL);     // 0.5MB (512,512)
  ushort* w2T     = (ushort*)(w + 171442176UL);     // 1MB (1024,512)
  float*  partial = (float*)(w + 172490752UL);      // 1MB: [8][16][2048]

  dim3 blk(256);
  dim3 blk512(512);

  // all weight transposes, one launch
  transpose_cvt_all<<<dim3(32, 32, 5), blk, 0, stream>>>(
      Wq, Wk, Wv, W1, W2, wqT, wkT, wvT, w1T, w2T);

  // merged QKV projections: one launch, grid z selects; q->f32, k/v->bf16
  gemm_tn_pipe<4, true, false, true><<<dim3(4, 128, 3), blk512, 0, stream>>>(
      q, wqT, bq, nullptr, out_res, kp_bf, nullptr,
      k, v, wkT, wvT, bk, bv, vp_bf,
      16384, 512, 1024, 0, 0, 0, 0);

  // merged per-token LayerNorms (1/sqrt(DK) folded into qn)
  ln3_kernel<<<dim3(4096, 3), blk, 0, stream>>>(
      out_res, kp_bf, vp_bf, g_q, be_q, g_k, be_k, g_v, be_v, qn, kn, vn);

  // vn -> vnT for PV's B-operand
  transpose_bf16<<<dim3(16, 64, 8), blk, 0, stream>>>(vn, vnT, 2048, 512);

  // scores: exp(qn.kn^T) masked -> bf16 (unnormalized) + per-block row-sum partials
  gemm_tn_pipe<2, false, true, false><<<dim3(16, 16, 8), blk512, 0, stream>>>(
      qn, kn, nullptr, mask, nullptr, attn_bf, partial,
      nullptr, nullptr, nullptr, nullptr, nullptr, nullptr, nullptr,
      2048, 2048, 512,
      (long)2048 * 512, (long)2048 * 512, (long)2048 * 2048, (long)2048 * 2048);

  // PV: invZ computed in-prologue from partials; row-scale epilogue +
  // fused normalized f32 attn write (block bx writes column quarter bx)
  gemm_tn_pipe<3, false, true, false><<<dim3(4, 16, 8), blk512, 0, stream>>>(
      attn_bf, vnT, nullptr, nullptr, out_attn, pv, partial,
      nullptr, nullptr, nullptr, nullptr, nullptr, nullptr, nullptr,
      2048, 512, 2048,
      (long)2048 * 2048, (long)512 * 2048, (long)2048 * 512, 0);

  // MLP
  gemm_tn_pipe<1, true, true, false><<<dim3(4, 128, 1), blk512, 0, stream>>>(
      pv, w1T, b1, nullptr, nullptr, h, nullptr,
      nullptr, nullptr, nullptr, nullptr, nullptr, nullptr, nullptr,
      16384, 512, 512, 0, 0, 0, 0);
  gemm_tn_pipe<0, true, false, false><<<dim3(8, 128, 1), blk512, 0, stream>>>(
      h, w2T, b2, nullptr, out_mlp, nullptr, nullptr,
      nullptr, nullptr, nullptr, nullptr, nullptr, nullptr, nullptr,
      16384, 1024, 512, 0, 0, 0, 0);
}

// Round 8
// 370.253 us; speedup vs baseline: 1.0457x; 1.0457x over previous
//
#include <hip/hip_runtime.h>
#include <hip/hip_bf16.h>

typedef __attribute__((ext_vector_type(8))) short short8;
typedef __attribute__((ext_vector_type(4))) short short4v;
typedef __attribute__((ext_vector_type(4))) float f32x4;

#define INV_TEMP 0.044194173824159216f

__device__ __forceinline__ ushort f2bf(float f) {
  unsigned u = __float_as_uint(f);
  unsigned r = (u + 0x7FFFu + ((u >> 16) & 1u)) >> 16;   // RNE
  return (ushort)r;
}
__device__ __forceinline__ float bf2f(ushort u) {
  union { unsigned i; float f; } x; x.i = ((unsigned)u) << 16; return x.f;
}

// async global->LDS, 16B per lane. LDS dest = wave-uniform base + lane*16;
// global source is per-lane (carries the inverse swizzle).
__device__ __forceinline__ void gload_lds16(const void* g, void* l) {
  __builtin_amdgcn_global_load_lds(
      (const __attribute__((address_space(1))) unsigned int*)(unsigned long long)(uintptr_t)g,
      (__attribute__((address_space(3))) unsigned int*)(unsigned)(uintptr_t)l,
      16, 0, 0);
}

// ---------------- mask (int32) -> bitmask, 32x compression ----------------
// word w covers mask[w*32 .. w*32+31]; bit j = (mask[w*32+j] != 0)
__global__ __launch_bounds__(256)
void mask_bits_kernel(const int* __restrict__ mask, unsigned* __restrict__ bits) {
  const long wIdx = (long)blockIdx.x * 256 + threadIdx.x;   // 1,048,576 words
  const int* p = mask + wIdx * 32;
  unsigned b = 0;
  #pragma unroll
  for (int i = 0; i < 8; i++) {
    int4 v = *(const int4*)(p + i * 4);
    b |= (v.x != 0 ? 1u : 0u) << (i * 4);
    b |= (v.y != 0 ? 1u : 0u) << (i * 4 + 1);
    b |= (v.z != 0 ? 1u : 0u) << (i * 4 + 2);
    b |= (v.w != 0 ? 1u : 0u) << (i * 4 + 3);
  }
  bits[wIdx] = b;
}

// ---------------- all weight transposes in one launch ----------------
__global__ __launch_bounds__(256)
void transpose_cvt_all(const float* __restrict__ Wq, const float* __restrict__ Wk,
                       const float* __restrict__ Wv, const float* __restrict__ W1,
                       const float* __restrict__ W2,
                       ushort* __restrict__ Tq, ushort* __restrict__ Tk,
                       ushort* __restrict__ Tv, ushort* __restrict__ T1,
                       ushort* __restrict__ T2) {
  const int z = blockIdx.z;
  const int K = (z < 3) ? 1024 : 512;
  const int N = (z == 4) ? 1024 : 512;
  if (blockIdx.x * 32 >= N || blockIdx.y * 32 >= K) return;
  const float* W = z == 0 ? Wq : (z == 1 ? Wk : (z == 2 ? Wv : (z == 3 ? W1 : W2)));
  ushort* WT = z == 0 ? Tq : (z == 1 ? Tk : (z == 2 ? Tv : (z == 3 ? T1 : T2)));
  __shared__ float tile[32][33];
  const int n0 = blockIdx.x * 32, k0 = blockIdx.y * 32;
  const int tx = threadIdx.x & 31, ty = threadIdx.x >> 5;
  #pragma unroll
  for (int i = ty; i < 32; i += 8)
    tile[i][tx] = W[(long)(k0 + i) * N + n0 + tx];
  __syncthreads();
  #pragma unroll
  for (int i = ty; i < 32; i += 8)
    WT[(long)(n0 + i) * K + k0 + tx] = f2bf(tile[tx][i]);
}

// ---------------- bf16 transpose per batch: in (S,D) -> out (D,S) ----------------
__global__ __launch_bounds__(256)
void transpose_bf16(const ushort* __restrict__ in, ushort* __restrict__ out, int S, int D) {
  __shared__ ushort tile[32][33];
  const ushort* inb = in + (long)blockIdx.z * S * D;
  ushort* outb = out + (long)blockIdx.z * S * D;
  const int d0 = blockIdx.x * 32, s0 = blockIdx.y * 32;
  const int tx = threadIdx.x & 31, ty = threadIdx.x >> 5;
  #pragma unroll
  for (int i = ty; i < 32; i += 8)
    tile[i][tx] = inb[(long)(s0 + i) * D + d0 + tx];
  __syncthreads();
  #pragma unroll
  for (int i = ty; i < 32; i += 8)
    outb[(long)(d0 + i) * S + s0 + tx] = tile[tx][i];
}

// ---------------- merged LayerNorm over D=512: q from f32, k/v from bf16 ----------------
__global__ __launch_bounds__(256)
void ln3_kernel(const float* __restrict__ Xq, const ushort* __restrict__ Xk,
                const ushort* __restrict__ Xv,
                const float* __restrict__ gq, const float* __restrict__ beq,
                const float* __restrict__ gk, const float* __restrict__ bek,
                const float* __restrict__ gv, const float* __restrict__ bev,
                ushort* __restrict__ Oq, ushort* __restrict__ Ok, ushort* __restrict__ Ov) {
  const int which = blockIdx.y;
  const float* g = which == 0 ? gq : (which == 1 ? gk : gv);
  const float* be = which == 0 ? beq : (which == 1 ? bek : bev);
  ushort* out = which == 0 ? Oq : (which == 1 ? Ok : Ov);
  const float scale = which == 0 ? INV_TEMP : 1.0f;

  const int row = blockIdx.x * 4 + (threadIdx.x >> 6);
  const int lane = threadIdx.x & 63;
  f32x4 v0, v1;
  if (which == 0) {
    const float* x = Xq + (long)row * 512 + lane * 8;
    v0 = *(const f32x4*)x;
    v1 = *(const f32x4*)(x + 4);
  } else {
    const ushort* x = (which == 1 ? Xk : Xv) + (long)row * 512 + lane * 8;
    short8 vv = *(const short8*)x;
    #pragma unroll
    for (int j = 0; j < 4; j++) { v0[j] = bf2f((ushort)vv[j]); v1[j] = bf2f((ushort)vv[4 + j]); }
  }
  float s = v0[0]+v0[1]+v0[2]+v0[3]+v1[0]+v1[1]+v1[2]+v1[3];
  float ss = v0[0]*v0[0]+v0[1]*v0[1]+v0[2]*v0[2]+v0[3]*v0[3]
           + v1[0]*v1[0]+v1[1]*v1[1]+v1[2]*v1[2]+v1[3]*v1[3];
  #pragma unroll
  for (int off = 32; off; off >>= 1) { s += __shfl_xor(s, off); ss += __shfl_xor(ss, off); }
  const float mean = s * (1.0f/512.0f);
  const float var  = ss * (1.0f/512.0f) - mean*mean;
  const float rs = rsqrtf(var + 1e-6f);
  f32x4 g0 = *(const f32x4*)(g + lane*8);
  f32x4 g1 = *(const f32x4*)(g + lane*8 + 4);
  f32x4 b0 = *(const f32x4*)(be + lane*8);
  f32x4 b1 = *(const f32x4*)(be + lane*8 + 4);
  union { short8 v; ushort u[8]; } o;
  #pragma unroll
  for (int j = 0; j < 4; j++) o.u[j]     = f2bf(((v0[j]-mean)*rs*g0[j] + b0[j]) * scale);
  #pragma unroll
  for (int j = 0; j < 4; j++) o.u[4 + j] = f2bf(((v1[j]-mean)*rs*g1[j] + b1[j]) * scale);
  *(short8*)(out + (long)row * 512 + lane * 8) = o.v;
}

// ---------------- pipelined TN GEMM: C[M,N] = A[M,K] * BT[N,K]^T ----------------
// 256 threads, 4 waves (2M x 2N), per-wave 64x64 output, BK=64, double-buffered
// LDS, 2-tile-ahead async staging, counted vmcnt (never 0 in steady state).
// EPI: 0 none, 1 relu, 2 exp + BITMASK + row-sum partials,
//      3 invZ-from-partials row-scale + fused normalized-f32-attn write,
//      4 merged QKV projections (grid z selects A/B/bias/output; A is f32).
template<int EPI, bool HAS_BIAS, bool OUT_BF16, bool A_F32>
__global__ __launch_bounds__(256)
void gemm_tn_pipe(const void* __restrict__ Av, const ushort* __restrict__ Bt,
                  const float* __restrict__ bias, const unsigned* __restrict__ mbits,
                  float* __restrict__ Cf, ushort* __restrict__ Cb,
                  float* __restrict__ partial,
                  const float* __restrict__ A2, const float* __restrict__ A3,
                  const ushort* __restrict__ Bt2, const ushort* __restrict__ Bt3,
                  const float* __restrict__ bias2, const float* __restrict__ bias3,
                  ushort* __restrict__ Cb2,
                  int M, int N, int K,
                  long sA, long sB, long sC) {
  __shared__ ushort As[2][128 * 64];
  __shared__ ushort Bs[2][128 * 64];
  __shared__ float zloc[128];
  const int tid = threadIdx.x;
  const int lane = tid & 63;
  const int wave = tid >> 6;       // 0..3
  const int wr = wave >> 1;        // 0..1  (64-row slab)
  const int wc = wave & 1;         // 0..1  (64-col slab)

  // ---- XCD-aware bijective chunk swizzle (T1) ----
  const int gx = gridDim.x, gy = gridDim.y;
  int lin = blockIdx.x + gx * (blockIdx.y + gy * blockIdx.z);
  const int nwg = gx * gy * (int)gridDim.z;
  int swz = lin;
  if ((nwg & 7) == 0) {
    const int q8 = nwg >> 3;
    swz = (lin & 7) * q8 + (lin >> 3);
  }
  const int bx = swz % gx;
  const int tmp = swz / gx;
  const int by = tmp % gy;
  const int bz = tmp / gy;

  const long zb = bz;
  const float* Afp;
  const ushort* Bb;
  const float* bias_p = bias;
  if constexpr (EPI == 4) {
    Afp = (bz == 0 ? (const float*)Av : (bz == 1 ? A2 : A3)) + (long)by * 128 * K;
    Bb = (bz == 0 ? Bt : (bz == 1 ? Bt2 : Bt3)) + (long)bx * 128 * K;
    bias_p = bz == 0 ? bias : (bz == 1 ? bias2 : bias3);
  } else {
    Afp = (const float*)Av + zb * sA + (long)by * 128 * K;
    Bb = Bt + zb * sB + (long)bx * 128 * K;
  }
  const ushort* Ab = (const ushort*)Av + zb * sA + (long)by * 128 * K;
  const int rowbase0 = by * 128;
  const int nt = K >> 6;

  if constexpr (EPI == 3) {
    if (tid < 128) {
      float z = 0.f;
      #pragma unroll
      for (int j = 0; j < 16; j++)
        z += partial[((long)(zb * 16 + j)) * 2048 + rowbase0 + tid];
      zloc[tid] = 1.0f / z;
    }
  }

  // stage K-tile t into buffer buf.
  // bf16: 8 async gloads (A,B x4). A_F32/EPI4: 8 f32x4 A loads -> 4 B gloads
  // -> cvt + swizzled ds_write x4 -> lgkmcnt(0) (cross-wave visibility).
  auto stage = [&](int buf, int t) {
    const long kt = (long)t << 6;
    if constexpr (A_F32) {
      f32x4 a[4][2];
      #pragma unroll
      for (int i = 0; i < 4; i++) {
        const int c = i * 256 + tid;
        const int row = c >> 3, g = c & 7;
        const float* p = Afp + (long)row * K + kt + g * 8;
        a[i][0] = *(const f32x4*)p;
        a[i][1] = *(const f32x4*)(p + 4);
      }
      #pragma unroll
      for (int i = 0; i < 4; i++) {
        const int c = i * 256 + tid;
        const int row = c >> 3, g = c & 7, gsrc = g ^ (row & 7);
        gload_lds16(Bb + (long)row * K + kt + gsrc * 8, (char*)Bs[buf] + c * 16);
      }
      #pragma unroll
      for (int i = 0; i < 4; i++) {
        const int c = i * 256 + tid;
        const int row = c >> 3, g = c & 7;
        union { short8 s; ushort u[8]; } o;
        #pragma unroll
        for (int j = 0; j < 4; j++) { o.u[j] = f2bf(a[i][0][j]); o.u[4 + j] = f2bf(a[i][1][j]); }
        *(short8*)((char*)As[buf] + ((row << 7) | ((g << 4) ^ ((row & 7) << 4)))) = o.s;
      }
      asm volatile("s_waitcnt lgkmcnt(0)" ::: "memory");
    } else {
      #pragma unroll
      for (int i = 0; i < 4; i++) {
        const int c = i * 256 + tid;
        const int row = c >> 3, g = c & 7, gsrc = g ^ (row & 7);
        gload_lds16(Ab + (long)row * K + kt + gsrc * 8, (char*)As[buf] + c * 16);
        gload_lds16(Bb + (long)row * K + kt + gsrc * 8, (char*)Bs[buf] + c * 16);
      }
    }
  };

  f32x4 acc[4][4];
  #pragma unroll
  for (int m = 0; m < 4; m++)
    #pragma unroll
    for (int n = 0; n < 4; n++)
      acc[m][n] = f32x4{0.f, 0.f, 0.f, 0.f};

  // prologue: two tiles in flight
  stage(0, 0);
  stage(1, 1);

  for (int t = 0; t < nt; ++t) {
    const int buf = t & 1;
    // drain tile t's staging; leave tile t+1's loads in flight (counted vmcnt)
    if (t == nt - 1) {
      asm volatile("s_waitcnt vmcnt(0)" ::: "memory");
    } else if constexpr (A_F32) {
      asm volatile("s_waitcnt vmcnt(4)" ::: "memory");
    } else {
      asm volatile("s_waitcnt vmcnt(8)" ::: "memory");
    }
    __builtin_amdgcn_s_barrier();          // tile-t data visible to all waves
    __builtin_amdgcn_sched_barrier(0);

    // fused normalized-attn f32 write (PV): block bx owns column quarter bx
    if constexpr (EPI == 3) {
      if ((t >> 3) == bx) {
        #pragma unroll
        for (int e = 0; e < 4; e++) {
          const int c = e * 256 + tid;
          const int row = c >> 3, g = c & 7;
          short8 p8 = *(const short8*)((const char*)As[buf] +
                       ((row << 7) | ((g ^ (row & 7)) << 4)));
          const float iz = zloc[row];
          f32x4 o0, o1;
          #pragma unroll
          for (int jj = 0; jj < 4; jj++) {
            o0[jj] = bf2f((ushort)p8[jj]) * iz;
            o1[jj] = bf2f((ushort)p8[4 + jj]) * iz;
          }
          float* dst = Cf + zb * 4194304L + (long)(rowbase0 + row) * 2048 + (t << 6) + g * 8;
          *(f32x4*)dst = o0;
          *(f32x4*)(dst + 4) = o1;
        }
      }
    }

    #pragma unroll
    for (int ks = 0; ks < 2; ks++) {
      short8 af[4], bfr[4];
      const int kb = ks * 64 + ((lane >> 4) << 4);
      #pragma unroll
      for (int m = 0; m < 4; m++) {
        const int row = wr * 64 + m * 16 + (lane & 15);
        af[m] = *(const short8*)((const char*)As[buf] +
                 ((row << 7) | (kb ^ ((row & 7) << 4))));
      }
      #pragma unroll
      for (int n = 0; n < 4; n++) {
        const int col = wc * 64 + n * 16 + (lane & 15);
        bfr[n] = *(const short8*)((const char*)Bs[buf] +
                  ((col << 7) | (kb ^ ((col & 7) << 4))));
      }
      __builtin_amdgcn_s_setprio(1);
      #pragma unroll
      for (int m = 0; m < 4; m++)
        #pragma unroll
        for (int n = 0; n < 4; n++)
          acc[m][n] = __builtin_amdgcn_mfma_f32_16x16x32_bf16(af[m], bfr[n], acc[m][n], 0, 0, 0);
      __builtin_amdgcn_s_setprio(0);
    }
    __builtin_amdgcn_sched_barrier(0);
    __builtin_amdgcn_s_barrier();          // all waves done reading buf
    __builtin_amdgcn_sched_barrier(0);
    if (t + 2 < nt) stage(buf, t + 2);     // overwrite just-read buffer
  }

  // epilogue: D[row][col], col = lane&15, row = (lane>>4)*4 + r  [m89/m91 layout]
  const int colbase = bx * 128 + wc * 64;
  const int rowbase = by * 128 + wr * 64;
  const int c_lane = lane & 15;
  const int r_lane = (lane >> 4) << 2;

  float rs_acc[4][4];
  unsigned mw[4][4][2];
  if constexpr (EPI == 2) {
    // preload bitmask words (L2-resident, 4MB/batch region): word0 covers
    // n=0,1 (cols colbase..+31); word1 covers n=2,3 (cols colbase+32..+63)
    #pragma unroll
    for (int m = 0; m < 4; m++)
      #pragma unroll
      for (int r4 = 0; r4 < 4; r4++) {
        const int row = rowbase + m * 16 + r_lane + r4;
        const unsigned* pw = mbits + zb * 131072L + (long)row * 64 + (colbase >> 5);
        mw[m][r4][0] = pw[0];
        mw[m][r4][1] = pw[1];
        rs_acc[m][r4] = 0.f;
      }
  }

  #pragma unroll
  for (int n = 0; n < 4; n++) {
    const int col = colbase + n * 16 + c_lane;
    const float bv = HAS_BIAS ? bias_p[col] : 0.0f;
    #pragma unroll
    for (int m = 0; m < 4; m++) {
      const int rbase = rowbase + m * 16 + r_lane;
      #pragma unroll
      for (int r4 = 0; r4 < 4; r4++) {
        const int row = rbase + r4;
        float vv = acc[m][n][r4] + bv;
        if constexpr (EPI == 1) vv = fmaxf(vv, 0.0f);
        if constexpr (EPI == 2) {
          const unsigned mk = (mw[m][r4][n >> 1] >> ((n * 16 + c_lane) & 31)) & 1u;
          vv = mk ? __expf(vv) : 0.0f;
          rs_acc[m][r4] += vv;
        }
        if constexpr (EPI == 3) vv *= zloc[wr * 64 + m * 16 + r_lane + r4];
        const long off = zb * sC + (long)row * N + col;
        if constexpr (EPI == 4) {
          if (bz == 0) Cf[off] = vv;
          else if (bz == 1) Cb[off] = f2bf(vv);
          else Cb2[off] = f2bf(vv);
        } else if constexpr (OUT_BF16) {
          Cb[off] = f2bf(vv);
        } else {
          Cf[off] = vv;
        }
      }
    }
  }

  if constexpr (EPI == 2) {
    // deterministic per-block row sums: 16-lane reduce -> LDS -> sum both wc waves
    __syncthreads();                        // As free for reuse as scratch
    float (*red)[128] = (float(*)[128])As;
    #pragma unroll
    for (int m = 0; m < 4; m++)
      #pragma unroll
      for (int r4 = 0; r4 < 4; r4++) {
        float vsum = rs_acc[m][r4];
        vsum += __shfl_xor(vsum, 1);
        vsum += __shfl_xor(vsum, 2);
        vsum += __shfl_xor(vsum, 4);
        vsum += __shfl_xor(vsum, 8);
        if (c_lane == 0) red[wc][wr * 64 + m * 16 + r_lane + r4] = vsum;
      }
    __syncthreads();
    if (tid < 128)
      partial[((long)zb * 16 + bx) * 2048 + by * 128 + tid] = red[0][tid] + red[1][tid];
  }
}

extern "C" void kernel_launch(void* const* d_in, const int* in_sizes, int n_in,
                              void* d_out, int out_size, void* d_ws, size_t ws_size,
                              hipStream_t stream) {
  const float* q    = (const float*)d_in[0];
  const float* k    = (const float*)d_in[1];
  const float* v    = (const float*)d_in[2];
  const int*   mask = (const int*)d_in[3];
  const float* Wq   = (const float*)d_in[4];
  const float* bq   = (const float*)d_in[5];
  const float* Wk   = (const float*)d_in[6];
  const float* bk   = (const float*)d_in[7];
  const float* Wv   = (const float*)d_in[8];
  const float* bv   = (const float*)d_in[9];
  const float* g_q  = (const float*)d_in[10];
  const float* be_q = (const float*)d_in[11];
  const float* g_k  = (const float*)d_in[12];
  const float* be_k = (const float*)d_in[13];
  const float* g_v  = (const float*)d_in[14];
  const float* be_v = (const float*)d_in[15];
  const float* W1   = (const float*)d_in[16];
  const float* b1   = (const float*)d_in[17];
  const float* W2   = (const float*)d_in[18];
  const float* b2   = (const float*)d_in[19];

  float* out_mlp  = (float*)d_out;                 // (8,2048,1024)
  float* out_res  = out_mlp + 16777216L;           // (8,2048,1,512)
  float* out_attn = out_res + 8388608L;            // (8,2048,2048)

  char* w = (char*)d_ws;
  ushort* qn      = (ushort*)(w);                   // 16.7MB
  ushort* kn      = (ushort*)(w + 16777216UL);      // 16.7MB
  ushort* kp_bf   = (ushort*)(w + 33554432UL);      // 16.7MB (dead after ln3)
  ushort* vp_bf   = (ushort*)(w + 50331648UL);      // 16.7MB (dead after ln3)
  ushort* attn_bf = (ushort*)(w + 33554432UL);      // 67MB, overlaps kp_bf/vp_bf
  ushort* vn      = (ushort*)(w + 100663296UL);     // 16.7MB
  ushort* vnT     = (ushort*)(w + 117440512UL);     // 16.7MB
  ushort* pv      = (ushort*)(w + 134217728UL);     // 16.7MB
  ushort* h       = (ushort*)(w + 150994944UL);     // 16.7MB (also holds mbits pre-MLP1)
  unsigned* mbits = (unsigned*)(w + 150994944UL);   // 4.2MB: [8][2048][64] words
  ushort* wqT     = (ushort*)(w + 167772160UL);     // 1MB (512,1024)
  ushort* wkT     = (ushort*)(w + 168820736UL);
  ushort* wvT     = (ushort*)(w + 169869312UL);
  ushort* w1T     = (ushort*)(w + 170917888UL);     // 0.5MB (512,512)
  ushort* w2T     = (ushort*)(w + 171442176UL);     // 1MB (1024,512)
  float*  partial = (float*)(w + 172490752UL);      // 1MB: [8][16][2048]

  dim3 blk(256);

  // all weight transposes, one launch
  transpose_cvt_all<<<dim3(32, 32, 5), blk, 0, stream>>>(
      Wq, Wk, Wv, W1, W2, wqT, wkT, wvT, w1T, w2T);

  // mask -> bitmask (32x compression; scores reads L2-resident words)
  mask_bits_kernel<<<4096, blk, 0, stream>>>(mask, mbits);

  // merged QKV projections: one launch, grid z selects; q->f32, k/v->bf16
  gemm_tn_pipe<4, true, false, true><<<dim3(4, 128, 3), blk, 0, stream>>>(
      q, wqT, bq, nullptr, out_res, kp_bf, nullptr,
      k, v, wkT, wvT, bk, bv, vp_bf,
      16384, 512, 1024, 0, 0, 0);

  // merged per-token LayerNorms (1/sqrt(DK) folded into qn)
  ln3_kernel<<<dim3(4096, 3), blk, 0, stream>>>(
      out_res, kp_bf, vp_bf, g_q, be_q, g_k, be_k, g_v, be_v, qn, kn, vn);

  // vn -> vnT for PV's B-operand
  transpose_bf16<<<dim3(16, 64, 8), blk, 0, stream>>>(vn, vnT, 2048, 512);

  // scores: exp(qn.kn^T) bitmasked -> bf16 (unnormalized) + row-sum partials
  gemm_tn_pipe<2, false, true, false><<<dim3(16, 16, 8), blk, 0, stream>>>(
      qn, kn, nullptr, mbits, nullptr, attn_bf, partial,
      nullptr, nullptr, nullptr, nullptr, nullptr, nullptr, nullptr,
      2048, 2048, 512,
      (long)2048 * 512, (long)2048 * 512, (long)2048 * 2048);

  // PV: invZ computed in-prologue from partials; row-scale epilogue +
  // fused normalized f32 attn write (block bx writes column quarter bx)
  gemm_tn_pipe<3, false, true, false><<<dim3(4, 16, 8), blk, 0, stream>>>(
      attn_bf, vnT, nullptr, nullptr, out_attn, pv, partial,
      nullptr, nullptr, nullptr, nullptr, nullptr, nullptr, nullptr,
      2048, 512, 2048,
      (long)2048 * 2048, (long)512 * 2048, (long)2048 * 512);

  // MLP
  gemm_tn_pipe<1, true, true, false><<<dim3(4, 128, 1), blk, 0, stream>>>(
      pv, w1T, b1, nullptr, nullptr, h, nullptr,
      nullptr, nullptr, nullptr, nullptr, nullptr, nullptr, nullptr,
      16384, 512, 512, 0, 0, 0);
  gemm_tn_pipe<0, true, false, false><<<dim3(8, 128, 1), blk, 0, stream>>>(
      h, w2T, b2, nullptr, out_mlp, nullptr, nullptr,
      nullptr, nullptr, nullptr, nullptr, nullptr, nullptr, nullptr,
      16384, 1024, 512, 0, 0, 0);
}

// Round 9
// 352.547 us; speedup vs baseline: 1.0982x; 1.0502x over previous
//
#include <hip/hip_runtime.h>
#include <hip/hip_bf16.h>

typedef __attribute__((ext_vector_type(8))) short short8;
typedef __attribute__((ext_vector_type(4))) short short4v;
typedef __attribute__((ext_vector_type(4))) float f32x4;

#define INV_TEMP 0.044194173824159216f

__device__ __forceinline__ ushort f2bf(float f) {
  unsigned u = __float_as_uint(f);
  unsigned r = (u + 0x7FFFu + ((u >> 16) & 1u)) >> 16;   // RNE
  return (ushort)r;
}
__device__ __forceinline__ float bf2f(ushort u) {
  union { unsigned i; float f; } x; x.i = ((unsigned)u) << 16; return x.f;
}

// async global->LDS, 16B per lane. LDS dest = wave-uniform base + lane*16;
// global source is per-lane (carries the inverse swizzle).
__device__ __forceinline__ void gload_lds16(const void* g, void* l) {
  __builtin_amdgcn_global_load_lds(
      (const __attribute__((address_space(1))) unsigned int*)(unsigned long long)(uintptr_t)g,
      (__attribute__((address_space(3))) unsigned int*)(unsigned)(uintptr_t)l,
      16, 0, 0);
}

// ---------------- all weight transposes in one launch ----------------
__global__ __launch_bounds__(256)
void transpose_cvt_all(const float* __restrict__ Wq, const float* __restrict__ Wk,
                       const float* __restrict__ Wv, const float* __restrict__ W1,
                       const float* __restrict__ W2,
                       ushort* __restrict__ Tq, ushort* __restrict__ Tk,
                       ushort* __restrict__ Tv, ushort* __restrict__ T1,
                       ushort* __restrict__ T2) {
  const int z = blockIdx.z;
  const int K = (z < 3) ? 1024 : 512;
  const int N = (z == 4) ? 1024 : 512;
  if (blockIdx.x * 32 >= N || blockIdx.y * 32 >= K) return;
  const float* W = z == 0 ? Wq : (z == 1 ? Wk : (z == 2 ? Wv : (z == 3 ? W1 : W2)));
  ushort* WT = z == 0 ? Tq : (z == 1 ? Tk : (z == 2 ? Tv : (z == 3 ? T1 : T2)));
  __shared__ float tile[32][33];
  const int n0 = blockIdx.x * 32, k0 = blockIdx.y * 32;
  const int tx = threadIdx.x & 31, ty = threadIdx.x >> 5;
  #pragma unroll
  for (int i = ty; i < 32; i += 8)
    tile[i][tx] = W[(long)(k0 + i) * N + n0 + tx];
  __syncthreads();
  #pragma unroll
  for (int i = ty; i < 32; i += 8)
    WT[(long)(n0 + i) * K + k0 + tx] = f2bf(tile[tx][i]);
}

// ---------------- bf16 transpose per batch: in (S,D) -> out (D,S) ----------------
__global__ __launch_bounds__(256)
void transpose_bf16(const ushort* __restrict__ in, ushort* __restrict__ out, int S, int D) {
  __shared__ ushort tile[32][33];
  const ushort* inb = in + (long)blockIdx.z * S * D;
  ushort* outb = out + (long)blockIdx.z * S * D;
  const int d0 = blockIdx.x * 32, s0 = blockIdx.y * 32;
  const int tx = threadIdx.x & 31, ty = threadIdx.x >> 5;
  #pragma unroll
  for (int i = ty; i < 32; i += 8)
    tile[i][tx] = inb[(long)(s0 + i) * D + d0 + tx];
  __syncthreads();
  #pragma unroll
  for (int i = ty; i < 32; i += 8)
    outb[(long)(d0 + i) * S + s0 + tx] = tile[tx][i];
}

// ---------------- merged LayerNorm over D=512: q from f32, k/v from bf16 ----------------
__global__ __launch_bounds__(256)
void ln3_kernel(const float* __restrict__ Xq, const ushort* __restrict__ Xk,
                const ushort* __restrict__ Xv,
                const float* __restrict__ gq, const float* __restrict__ beq,
                const float* __restrict__ gk, const float* __restrict__ bek,
                const float* __restrict__ gv, const float* __restrict__ bev,
                ushort* __restrict__ Oq, ushort* __restrict__ Ok, ushort* __restrict__ Ov) {
  const int which = blockIdx.y;
  const float* g = which == 0 ? gq : (which == 1 ? gk : gv);
  const float* be = which == 0 ? beq : (which == 1 ? bek : bev);
  ushort* out = which == 0 ? Oq : (which == 1 ? Ok : Ov);
  const float scale = which == 0 ? INV_TEMP : 1.0f;

  const int row = blockIdx.x * 4 + (threadIdx.x >> 6);
  const int lane = threadIdx.x & 63;
  f32x4 v0, v1;
  if (which == 0) {
    const float* x = Xq + (long)row * 512 + lane * 8;
    v0 = *(const f32x4*)x;
    v1 = *(const f32x4*)(x + 4);
  } else {
    const ushort* x = (which == 1 ? Xk : Xv) + (long)row * 512 + lane * 8;
    short8 vv = *(const short8*)x;
    #pragma unroll
    for (int j = 0; j < 4; j++) { v0[j] = bf2f((ushort)vv[j]); v1[j] = bf2f((ushort)vv[4 + j]); }
  }
  float s = v0[0]+v0[1]+v0[2]+v0[3]+v1[0]+v1[1]+v1[2]+v1[3];
  float ss = v0[0]*v0[0]+v0[1]*v0[1]+v0[2]*v0[2]+v0[3]*v0[3]
           + v1[0]*v1[0]+v1[1]*v1[1]+v1[2]*v1[2]+v1[3]*v1[3];
  #pragma unroll
  for (int off = 32; off; off >>= 1) { s += __shfl_xor(s, off); ss += __shfl_xor(ss, off); }
  const float mean = s * (1.0f/512.0f);
  const float var  = ss * (1.0f/512.0f) - mean*mean;
  const float rs = rsqrtf(var + 1e-6f);
  f32x4 g0 = *(const f32x4*)(g + lane*8);
  f32x4 g1 = *(const f32x4*)(g + lane*8 + 4);
  f32x4 b0 = *(const f32x4*)(be + lane*8);
  f32x4 b1 = *(const f32x4*)(be + lane*8 + 4);
  union { short8 v; ushort u[8]; } o;
  #pragma unroll
  for (int j = 0; j < 4; j++) o.u[j]     = f2bf(((v0[j]-mean)*rs*g0[j] + b0[j]) * scale);
  #pragma unroll
  for (int j = 0; j < 4; j++) o.u[4 + j] = f2bf(((v1[j]-mean)*rs*g1[j] + b1[j]) * scale);
  *(short8*)(out + (long)row * 512 + lane * 8) = o.v;
}

// ---------------- pipelined TN GEMM: C[M,N] = A[M,K] * BT[N,K]^T ----------------
// 256 threads, 4 waves (2M x 2N), per-wave 64x64 output, BK=64, double-buffered
// LDS, 2-tile-ahead async staging, counted vmcnt (never 0 in steady state).
// EPI: 0 none, 1 relu,
//      2 exp + direct int4 mask + COALESCED epilogue (LDS-transpose, vectorized
//        stores, per-row sums -> partial),
//      3 invZ-from-partials row-scale + fused normalized-f32-attn write,
//      4 merged QKV projections (grid z selects A/B/bias/output; A is f32).
template<int EPI, bool HAS_BIAS, bool OUT_BF16, bool A_F32>
__global__ __launch_bounds__(256)
void gemm_tn_pipe(const void* __restrict__ Av, const ushort* __restrict__ Bt,
                  const float* __restrict__ bias, const int* __restrict__ maskp,
                  float* __restrict__ Cf, ushort* __restrict__ Cb,
                  float* __restrict__ partial,
                  const float* __restrict__ A2, const float* __restrict__ A3,
                  const ushort* __restrict__ Bt2, const ushort* __restrict__ Bt3,
                  const float* __restrict__ bias2, const float* __restrict__ bias3,
                  ushort* __restrict__ Cb2,
                  int M, int N, int K,
                  long sA, long sB, long sC) {
  // one raw LDS block, carved: As 2x16KB | Bs 2x16KB | zloc 512B.
  // EPI==2 epilogue reuses the front 34KB as a [64][132] f32 transpose pane.
  __shared__ char smem_raw[66048];
  ushort (*As)[128 * 64] = (ushort(*)[128 * 64])smem_raw;
  ushort (*Bs)[128 * 64] = (ushort(*)[128 * 64])(smem_raw + 32768);
  float* zloc = (float*)(smem_raw + 65536);
  float* smf  = (float*)smem_raw;            // [64][132] epilogue pane (EPI 2)

  const int tid = threadIdx.x;
  const int lane = tid & 63;
  const int wave = tid >> 6;       // 0..3
  const int wr = wave >> 1;        // 0..1  (64-row slab)
  const int wc = wave & 1;         // 0..1  (64-col slab)

  // ---- XCD-aware bijective chunk swizzle (T1) ----
  const int gx = gridDim.x, gy = gridDim.y;
  int lin = blockIdx.x + gx * (blockIdx.y + gy * blockIdx.z);
  const int nwg = gx * gy * (int)gridDim.z;
  int swz = lin;
  if ((nwg & 7) == 0) {
    const int q8 = nwg >> 3;
    swz = (lin & 7) * q8 + (lin >> 3);
  }
  const int bx = swz % gx;
  const int tmp = swz / gx;
  const int by = tmp % gy;
  const int bz = tmp / gy;

  const long zb = bz;
  const float* Afp;
  const ushort* Bb;
  const float* bias_p = bias;
  if constexpr (EPI == 4) {
    Afp = (bz == 0 ? (const float*)Av : (bz == 1 ? A2 : A3)) + (long)by * 128 * K;
    Bb = (bz == 0 ? Bt : (bz == 1 ? Bt2 : Bt3)) + (long)bx * 128 * K;
    bias_p = bz == 0 ? bias : (bz == 1 ? bias2 : bias3);
  } else {
    Afp = (const float*)Av + zb * sA + (long)by * 128 * K;
    Bb = Bt + zb * sB + (long)bx * 128 * K;
  }
  const ushort* Ab = (const ushort*)Av + zb * sA + (long)by * 128 * K;
  const int rowbase0 = by * 128;
  const int nt = K >> 6;

  if constexpr (EPI == 3) {
    if (tid < 128) {
      float z = 0.f;
      #pragma unroll
      for (int j = 0; j < 16; j++)
        z += partial[((long)(zb * 16 + j)) * 2048 + rowbase0 + tid];
      zloc[tid] = 1.0f / z;
    }
  }

  // stage K-tile t into buffer buf.
  auto stage = [&](int buf, int t) {
    const long kt = (long)t << 6;
    if constexpr (A_F32) {
      f32x4 a[4][2];
      #pragma unroll
      for (int i = 0; i < 4; i++) {
        const int c = i * 256 + tid;
        const int row = c >> 3, g = c & 7;
        const float* p = Afp + (long)row * K + kt + g * 8;
        a[i][0] = *(const f32x4*)p;
        a[i][1] = *(const f32x4*)(p + 4);
      }
      #pragma unroll
      for (int i = 0; i < 4; i++) {
        const int c = i * 256 + tid;
        const int row = c >> 3, g = c & 7, gsrc = g ^ (row & 7);
        gload_lds16(Bb + (long)row * K + kt + gsrc * 8, (char*)Bs[buf] + c * 16);
      }
      #pragma unroll
      for (int i = 0; i < 4; i++) {
        const int c = i * 256 + tid;
        const int row = c >> 3, g = c & 7;
        union { short8 s; ushort u[8]; } o;
        #pragma unroll
        for (int j = 0; j < 4; j++) { o.u[j] = f2bf(a[i][0][j]); o.u[4 + j] = f2bf(a[i][1][j]); }
        *(short8*)((char*)As[buf] + ((row << 7) | ((g << 4) ^ ((row & 7) << 4)))) = o.s;
      }
      asm volatile("s_waitcnt lgkmcnt(0)" ::: "memory");
    } else {
      #pragma unroll
      for (int i = 0; i < 4; i++) {
        const int c = i * 256 + tid;
        const int row = c >> 3, g = c & 7, gsrc = g ^ (row & 7);
        gload_lds16(Ab + (long)row * K + kt + gsrc * 8, (char*)As[buf] + c * 16);
        gload_lds16(Bb + (long)row * K + kt + gsrc * 8, (char*)Bs[buf] + c * 16);
      }
    }
  };

  f32x4 acc[4][4];
  #pragma unroll
  for (int m = 0; m < 4; m++)
    #pragma unroll
    for (int n = 0; n < 4; n++)
      acc[m][n] = f32x4{0.f, 0.f, 0.f, 0.f};

  // prologue: two tiles in flight
  stage(0, 0);
  stage(1, 1);

  for (int t = 0; t < nt; ++t) {
    const int buf = t & 1;
    if (t == nt - 1) {
      asm volatile("s_waitcnt vmcnt(0)" ::: "memory");
    } else if constexpr (A_F32) {
      asm volatile("s_waitcnt vmcnt(4)" ::: "memory");
    } else {
      asm volatile("s_waitcnt vmcnt(8)" ::: "memory");
    }
    __builtin_amdgcn_s_barrier();          // tile-t data visible to all waves
    __builtin_amdgcn_sched_barrier(0);

    // fused normalized-attn f32 write (PV): block bx owns column quarter bx
    if constexpr (EPI == 3) {
      if ((t >> 3) == bx) {
        #pragma unroll
        for (int e = 0; e < 4; e++) {
          const int c = e * 256 + tid;
          const int row = c >> 3, g = c & 7;
          short8 p8 = *(const short8*)((const char*)As[buf] +
                       ((row << 7) | ((g ^ (row & 7)) << 4)));
          const float iz = zloc[row];
          f32x4 o0, o1;
          #pragma unroll
          for (int jj = 0; jj < 4; jj++) {
            o0[jj] = bf2f((ushort)p8[jj]) * iz;
            o1[jj] = bf2f((ushort)p8[4 + jj]) * iz;
          }
          float* dst = Cf + zb * 4194304L + (long)(rowbase0 + row) * 2048 + (t << 6) + g * 8;
          *(f32x4*)dst = o0;
          *(f32x4*)(dst + 4) = o1;
        }
      }
    }

    #pragma unroll
    for (int ks = 0; ks < 2; ks++) {
      short8 af[4], bfr[4];
      const int kb = ks * 64 + ((lane >> 4) << 4);
      #pragma unroll
      for (int m = 0; m < 4; m++) {
        const int row = wr * 64 + m * 16 + (lane & 15);
        af[m] = *(const short8*)((const char*)As[buf] +
                 ((row << 7) | (kb ^ ((row & 7) << 4))));
      }
      #pragma unroll
      for (int n = 0; n < 4; n++) {
        const int col = wc * 64 + n * 16 + (lane & 15);
        bfr[n] = *(const short8*)((const char*)Bs[buf] +
                  ((col << 7) | (kb ^ ((col & 7) << 4))));
      }
      __builtin_amdgcn_s_setprio(1);
      #pragma unroll
      for (int m = 0; m < 4; m++)
        #pragma unroll
        for (int n = 0; n < 4; n++)
          acc[m][n] = __builtin_amdgcn_mfma_f32_16x16x32_bf16(af[m], bfr[n], acc[m][n], 0, 0, 0);
      __builtin_amdgcn_s_setprio(0);
    }
    __builtin_amdgcn_sched_barrier(0);
    __builtin_amdgcn_s_barrier();          // all waves done reading buf
    __builtin_amdgcn_sched_barrier(0);
    if (t + 2 < nt) stage(buf, t + 2);     // overwrite just-read buffer
  }

  const int c_lane = lane & 15;
  const int r_lane = (lane >> 4) << 2;

  if constexpr (EPI == 2) {
    // ---- coalesced masked-exp epilogue: two 64-row half-passes ----
    // pass h: waves with wr==h dump acc -> smf[64][132]; then all 256 threads
    // own (row = tid>>2, col quarter = (tid&3)*32): vectorized LDS reads,
    // int4 mask loads, expf, short8 stores, 4-lane row-sum -> partial.
    const int r_own = tid >> 2;            // 0..63 local row
    const int cq    = (tid & 3) * 32;      // col quarter base
    #pragma unroll
    for (int h = 0; h < 2; h++) {
      __syncthreads();
      if (wr == h) {
        #pragma unroll
        for (int n = 0; n < 4; n++)
          #pragma unroll
          for (int m = 0; m < 4; m++)
            #pragma unroll
            for (int r4 = 0; r4 < 4; r4++)
              smf[(m * 16 + r_lane + r4) * 132 + wc * 64 + n * 16 + c_lane] =
                  acc[m][n][r4];
      }
      __syncthreads();
      const int grow = rowbase0 + h * 64 + r_own;
      const int gcolb = bx * 128 + cq;
      const int* mrow = maskp + zb * 4194304L + (long)grow * 2048 + gcolb;
      ushort* orow = Cb + zb * sC + (long)grow * 2048 + gcolb;
      float rsum = 0.f;
      #pragma unroll
      for (int cc = 0; cc < 4; cc++) {
        f32x4 v0 = *(const f32x4*)&smf[r_own * 132 + cq + cc * 8];
        f32x4 v1 = *(const f32x4*)&smf[r_own * 132 + cq + cc * 8 + 4];
        int4 m0 = *(const int4*)(mrow + cc * 8);
        int4 m1 = *(const int4*)(mrow + cc * 8 + 4);
        float e0 = m0.x ? __expf(v0[0]) : 0.f;
        float e1 = m0.y ? __expf(v0[1]) : 0.f;
        float e2 = m0.z ? __expf(v0[2]) : 0.f;
        float e3 = m0.w ? __expf(v0[3]) : 0.f;
        float e4 = m1.x ? __expf(v1[0]) : 0.f;
        float e5 = m1.y ? __expf(v1[1]) : 0.f;
        float e6 = m1.z ? __expf(v1[2]) : 0.f;
        float e7 = m1.w ? __expf(v1[3]) : 0.f;
        rsum += (e0 + e1 + e2 + e3) + (e4 + e5 + e6 + e7);
        union { short8 s; ushort u[8]; } o;
        o.u[0] = f2bf(e0); o.u[1] = f2bf(e1); o.u[2] = f2bf(e2); o.u[3] = f2bf(e3);
        o.u[4] = f2bf(e4); o.u[5] = f2bf(e5); o.u[6] = f2bf(e6); o.u[7] = f2bf(e7);
        *(short8*)(orow + cc * 8) = o.s;
      }
      rsum += __shfl_xor(rsum, 1);
      rsum += __shfl_xor(rsum, 2);
      if ((tid & 3) == 0)
        partial[((long)zb * 16 + bx) * 2048 + grow] = rsum;
    }
  } else {
    // generic epilogue: D[row][col], col = lane&15, row = (lane>>4)*4 + r
    const int colbase = bx * 128 + wc * 64;
    const int rowbase = by * 128 + wr * 64;
    #pragma unroll
    for (int n = 0; n < 4; n++) {
      const int col = colbase + n * 16 + c_lane;
      const float bv = HAS_BIAS ? bias_p[col] : 0.0f;
      #pragma unroll
      for (int m = 0; m < 4; m++) {
        const int rbase = rowbase + m * 16 + r_lane;
        #pragma unroll
        for (int r4 = 0; r4 < 4; r4++) {
          const int row = rbase + r4;
          float vv = acc[m][n][r4] + bv;
          if constexpr (EPI == 1) vv = fmaxf(vv, 0.0f);
          if constexpr (EPI == 3) vv *= zloc[wr * 64 + m * 16 + r_lane + r4];
          const long off = zb * sC + (long)row * N + col;
          if constexpr (EPI == 4) {
            if (bz == 0) Cf[off] = vv;
            else if (bz == 1) Cb[off] = f2bf(vv);
            else Cb2[off] = f2bf(vv);
          } else if constexpr (OUT_BF16) {
            Cb[off] = f2bf(vv);
          } else {
            Cf[off] = vv;
          }
        }
      }
    }
  }
}

extern "C" void kernel_launch(void* const* d_in, const int* in_sizes, int n_in,
                              void* d_out, int out_size, void* d_ws, size_t ws_size,
                              hipStream_t stream) {
  const float* q    = (const float*)d_in[0];
  const float* k    = (const float*)d_in[1];
  const float* v    = (const float*)d_in[2];
  const int*   mask = (const int*)d_in[3];
  const float* Wq   = (const float*)d_in[4];
  const float* bq   = (const float*)d_in[5];
  const float* Wk   = (const float*)d_in[6];
  const float* bk   = (const float*)d_in[7];
  const float* Wv   = (const float*)d_in[8];
  const float* bv   = (const float*)d_in[9];
  const float* g_q  = (const float*)d_in[10];
  const float* be_q = (const float*)d_in[11];
  const float* g_k  = (const float*)d_in[12];
  const float* be_k = (const float*)d_in[13];
  const float* g_v  = (const float*)d_in[14];
  const float* be_v = (const float*)d_in[15];
  const float* W1   = (const float*)d_in[16];
  const float* b1   = (const float*)d_in[17];
  const float* W2   = (const float*)d_in[18];
  const float* b2   = (const float*)d_in[19];

  float* out_mlp  = (float*)d_out;                 // (8,2048,1024)
  float* out_res  = out_mlp + 16777216L;           // (8,2048,1,512)
  float* out_attn = out_res + 8388608L;            // (8,2048,2048)

  char* w = (char*)d_ws;
  ushort* qn      = (ushort*)(w);                   // 16.7MB
  ushort* kn      = (ushort*)(w + 16777216UL);      // 16.7MB
  ushort* kp_bf   = (ushort*)(w + 33554432UL);      // 16.7MB (dead after ln3)
  ushort* vp_bf   = (ushort*)(w + 50331648UL);      // 16.7MB (dead after ln3)
  ushort* attn_bf = (ushort*)(w + 33554432UL);      // 67MB, overlaps kp_bf/vp_bf
  ushort* vn      = (ushort*)(w + 100663296UL);     // 16.7MB
  ushort* vnT     = (ushort*)(w + 117440512UL);     // 16.7MB
  ushort* pv      = (ushort*)(w + 134217728UL);     // 16.7MB
  ushort* h       = (ushort*)(w + 150994944UL);     // 16.7MB
  ushort* wqT     = (ushort*)(w + 167772160UL);     // 1MB (512,1024)
  ushort* wkT     = (ushort*)(w + 168820736UL);
  ushort* wvT     = (ushort*)(w + 169869312UL);
  ushort* w1T     = (ushort*)(w + 170917888UL);     // 0.5MB (512,512)
  ushort* w2T     = (ushort*)(w + 171442176UL);     // 1MB (1024,512)
  float*  partial = (float*)(w + 172490752UL);      // 1MB: [8][16][2048]

  dim3 blk(256);

  // all weight transposes, one launch
  transpose_cvt_all<<<dim3(32, 32, 5), blk, 0, stream>>>(
      Wq, Wk, Wv, W1, W2, wqT, wkT, wvT, w1T, w2T);

  // merged QKV projections: one launch, grid z selects; q->f32, k/v->bf16
  gemm_tn_pipe<4, true, false, true><<<dim3(4, 128, 3), blk, 0, stream>>>(
      q, wqT, bq, nullptr, out_res, kp_bf, nullptr,
      k, v, wkT, wvT, bk, bv, vp_bf,
      16384, 512, 1024, 0, 0, 0);

  // merged per-token LayerNorms (1/sqrt(DK) folded into qn)
  ln3_kernel<<<dim3(4096, 3), blk, 0, stream>>>(
      out_res, kp_bf, vp_bf, g_q, be_q, g_k, be_k, g_v, be_v, qn, kn, vn);

  // vn -> vnT for PV's B-operand
  transpose_bf16<<<dim3(16, 64, 8), blk, 0, stream>>>(vn, vnT, 2048, 512);

  // scores: exp(qn.kn^T) masked -> bf16 (unnormalized) + row-sum partials,
  // coalesced epilogue with direct int4 mask reads
  gemm_tn_pipe<2, false, true, false><<<dim3(16, 16, 8), blk, 0, stream>>>(
      qn, kn, nullptr, mask, nullptr, attn_bf, partial,
      nullptr, nullptr, nullptr, nullptr, nullptr, nullptr, nullptr,
      2048, 2048, 512,
      (long)2048 * 512, (long)2048 * 512, (long)2048 * 2048);

  // PV: invZ computed in-prologue from partials; row-scale epilogue +
  // fused normalized f32 attn write (block bx writes column quarter bx)
  gemm_tn_pipe<3, false, true, false><<<dim3(4, 16, 8), blk, 0, stream>>>(
      attn_bf, vnT, nullptr, nullptr, out_attn, pv, partial,
      nullptr, nullptr, nullptr, nullptr, nullptr, nullptr, nullptr,
      2048, 512, 2048,
      (long)2048 * 2048, (long)512 * 2048, (long)2048 * 512);

  // MLP
  gemm_tn_pipe<1, true, true, false><<<dim3(4, 128, 1), blk, 0, stream>>>(
      pv, w1T, b1, nullptr, nullptr, h, nullptr,
      nullptr, nullptr, nullptr, nullptr, nullptr, nullptr, nullptr,
      16384, 512, 512, 0, 0, 0);
  gemm_tn_pipe<0, true, false, false><<<dim3(8, 128, 1), blk, 0, stream>>>(
      h, w2T, b2, nullptr, out_mlp, nullptr, nullptr,
      nullptr, nullptr, nullptr, nullptr, nullptr, nullptr, nullptr,
      16384, 1024, 512, 0, 0, 0);
}